// Round 3
// baseline (144.246 us; speedup 1.0000x reference)
//
#include <hip/hip_runtime.h>

// Nearest-neighbor scatter-to-grid, two-kernel version:
//   K1: pts_ws[b][n] = {px, py, px^2+py^2, 0}   (32 KB in d_ws)
//   K2: per grid cell, argmin over N=1024 points using SCALAR (s_load) point
//       fetch — point data is wave-uniform, so keep it off the LDS/vector pipe.
//
// Bit-exactness contract (verified passing in round 2, absmax 0.0):
//  - pp  = round(px*px) + round(py*py)      (XLA fused mul+reduce, no FMA)
//  - dot = fma(gy, py, round(gx*px))        (Eigen gemm: sequential FMA, k asc.)
//  - d2  = round(pp - 2*dot)                (2*dot exact; single rounding)
//  - argmin: strict '<' ascending scan = first-occurrence tie-break

#define GRID_H 256
#define GRID_W 256
#define GRID_G (GRID_H * GRID_W)
#define NPTS   1024
#define BLOCK  256

__global__ __launch_bounds__(256) void prep_pts_kernel(
    const float* __restrict__ XY,   // [B, 2, N]
    float4*      __restrict__ pts,  // [B, N] {px,py,pp,0}
    int B, int N)
{
#pragma clang fp contract(off)
    int i = blockIdx.x * blockDim.x + threadIdx.x;   // i in [0, B*N)
    if (i >= B * N) return;
    int b = i / N;
    int n = i - b * N;
    const float* xb = XY + (size_t)b * 2 * N;
    float px = xb[n];
    float py = xb[N + n];
    float pp = px * px + py * py;    // contract(off): round(px^2)+round(py^2)
    pts[i] = make_float4(px, py, pp, 0.0f);
}

__global__ __launch_bounds__(BLOCK) void nn_scan_kernel(
    const float4* __restrict__ pts,  // [B, N]
    const float*  __restrict__ R,    // [B, C, N]
    float*        __restrict__ out,  // [B, C, H, W]
    int B, int C, int N)
{
#pragma clang fp contract(off)
    const int blk = blockIdx.x;        // [0, B*256)
    const int b   = blk >> 8;          // 256 blocks per batch
    const int y   = blk & 255;         // entire block shares one grid row y
    const int x   = threadIdx.x;

    const float gx = ((float)x + 0.5f) * (1.0f / GRID_W);
    const float gy = ((float)y + 0.5f) * (1.0f / GRID_H);

    // Uniform-address loop over points: compiler emits s_load_dwordxN
    // (scalar pipe), leaving VALU free for the 6-op argmin body.
    const float4* __restrict__ p = pts + (size_t)b * N;

    float best = 3.4e38f;
    int   bi   = 0;
    #pragma unroll 8
    for (int n = 0; n < NPTS; ++n) {
        float4 q = p[n];                     // wave-uniform -> SGPR load
        float  t   = gx * q.x;               // rounded mul
        float  dot = fmaf(gy, q.y, t);       // Eigen gemm rounding
        float  d2  = fmaf(-2.0f, dot, q.z);  // exact 2*dot, single rounding
        if (d2 < best) { best = d2; bi = n; }
    }

    const int g = y * GRID_W + x;
    const float* rb = R + (size_t)b * C * N;
    float*       ob = out + (size_t)b * C * GRID_G;
    #pragma unroll
    for (int c = 0; c < 4; ++c) {
        ob[(size_t)c * GRID_G + g] = rb[(size_t)c * N + bi];
    }
}

extern "C" void kernel_launch(void* const* d_in, const int* in_sizes, int n_in,
                              void* d_out, int out_size, void* d_ws, size_t ws_size,
                              hipStream_t stream) {
    const float* R  = (const float*)d_in[0];   // [B, C, N] f32
    const float* XY = (const float*)d_in[1];   // [B, 2, N] f32
    float* out = (float*)d_out;                // [B, C, H, W] f32

    const int N = NPTS;
    const int B = in_sizes[1] / (2 * N);       // 2
    const int C = in_sizes[0] / (B * N);       // 4

    float4* pts = (float4*)d_ws;               // B*N*16 = 32 KB scratch

    const int prep_threads = B * N;            // 2048
    prep_pts_kernel<<<(prep_threads + 255) / 256, 256, 0, stream>>>(XY, pts, B, N);

    const int nblocks = B * GRID_H;            // one block per (b, grid row) = 512
    nn_scan_kernel<<<nblocks, BLOCK, 0, stream>>>(pts, R, out, B, C, N);
}

// Round 4
// 112.651 us; speedup vs baseline: 1.2805x; 1.2805x over previous
//
#include <hip/hip_runtime.h>

// Nearest-neighbor scatter-to-grid, single kernel.
//   per cell: argmin_n (pp_n - 2*(gx*px_n + gy*py_n)), gather 4 channels.
//
// Pipe choice (round-3 lesson): point data is wave-uniform; SMEM s_load is
// drain-all (OOO returns -> lgkmcnt(0) only) and serializes on latency.
// Instead force VECTOR global loads (same-address broadcast, one L1 line,
// counted-vmcnt pipelining) via an opaque v_mov zero in the index.
//
// 2 cells/thread (same x -> shared t = gx*px; rows y and y+128) halves the
// load stream per cell and gives two independent argmin dep-chains.
//
// Bit-exactness contract (verified absmax 0.0 in rounds 2-3):
//  - pp  = round(px*px) + round(py*py)      (XLA fused mul+reduce, no FMA)
//  - dot = fma(gy, py, round(gx*px))        (Eigen gemm: sequential FMA)
//  - d2  = round(pp - 2*dot)                (2*dot exact; single rounding)
//  - argmin: strict '<' ascending scan = first-occurrence tie-break

#define GRID_H 256
#define GRID_W 256
#define GRID_G (GRID_H * GRID_W)
#define NPTS   1024
#define BLOCK  128

__global__ __launch_bounds__(BLOCK) void nn_scan2_kernel(
    const float* __restrict__ R,    // [B, C, N]
    const float* __restrict__ XY,   // [B, 2, N]
    float*       __restrict__ out,  // [B, C, H, W]
    int B, int C, int N)
{
#pragma clang fp contract(off)
    const int blk = blockIdx.x;          // [0, B*256)
    const int b   = blk >> 8;
    const int r   = blk & 255;
    const int y   = r >> 1;              // rows y and y+128
    const int x   = ((r & 1) << 7) + threadIdx.x;

    const float gx  = ((float)x + 0.5f) * (1.0f / GRID_W);
    const float gy0 = ((float)y + 0.5f) * (1.0f / GRID_H);
    const float gy1 = ((float)(y + 128) + 0.5f) * (1.0f / GRID_H);

    // Opaque zero: compiler can't prove it's uniform -> VGPR addressing ->
    // global_load (vector pipe, counted vmcnt) instead of s_load.
    int zero;
    asm volatile("v_mov_b32 %0, 0" : "=v"(zero));

    const float* __restrict__ px = XY + (size_t)b * 2 * N;
    const float* __restrict__ py = px + N;

    float best0 = 3.4e38f, best1 = 3.4e38f;
    int   bi0 = 0, bi1 = 0;

    #pragma unroll 8
    for (int n = 0; n < NPTS; ++n) {
        const int m = n + zero;              // per-lane (broadcast) address
        float qx = px[m];
        float qy = py[m];
        float pp = qx * qx + qy * qy;        // contract off: 2 mul + add
        float t  = gx * qx;                  // shared across the 2 cells
        float dot0 = fmaf(gy0, qy, t);
        float dot1 = fmaf(gy1, qy, t);
        float d20  = fmaf(-2.0f, dot0, pp);
        float d21  = fmaf(-2.0f, dot1, pp);
        if (d20 < best0) { best0 = d20; bi0 = n; }
        if (d21 < best1) { best1 = d21; bi1 = n; }
    }

    const int g0 = y * GRID_W + x;
    const int g1 = (y + 128) * GRID_W + x;
    const float* rb = R + (size_t)b * C * N;
    float*       ob = out + (size_t)b * C * GRID_G;
    #pragma unroll
    for (int c = 0; c < 4; ++c) {
        ob[(size_t)c * GRID_G + g0] = rb[(size_t)c * N + bi0];
        ob[(size_t)c * GRID_G + g1] = rb[(size_t)c * N + bi1];
    }
}

extern "C" void kernel_launch(void* const* d_in, const int* in_sizes, int n_in,
                              void* d_out, int out_size, void* d_ws, size_t ws_size,
                              hipStream_t stream) {
    const float* R  = (const float*)d_in[0];   // [B, C, N] f32
    const float* XY = (const float*)d_in[1];   // [B, 2, N] f32
    float* out = (float*)d_out;                // [B, C, H, W] f32

    const int N = NPTS;
    const int B = in_sizes[1] / (2 * N);       // 2
    const int C = in_sizes[0] / (B * N);       // 4

    const int nblocks = B * 256;               // 512 blocks x 128 threads
    nn_scan2_kernel<<<nblocks, BLOCK, 0, stream>>>(R, XY, out, B, C, N);
}

// Round 5
// 59.623 us; speedup vs baseline: 2.4193x; 1.8894x over previous
//
#include <hip/hip_runtime.h>

// Nearest-neighbor scatter-to-grid with per-tile candidate culling.
//
// Round-4 lesson: brute force = B*G*N = 134M evals, latency/issue bound at
// ~62 us. Algorithmic fix: one block per 16x16 cell tile; points farther
// from the tile center than dmin + 2r + eps can never be any cell's argmin
// (r = tile half-diagonal). ~40 survivors of 1024 -> ~25x less phase-2 work.
//
// Safety: phase-2 d2 uses the verified bit-exact formula; pruning margin
// eps = 8e-3 (distance units) >> 4x the max argmin displacement from f32
// formula rounding (sqrt(2*delta) ~ 2e-3, delta <= 1.3e-6). Compaction order
// is scrambled -> explicit (d2 < best) || (d2 == best && n < bi) tie-break
// == jnp.argmin first-occurrence. Worst case (no culling) stays correct.
//
// Bit-exactness contract (verified absmax 0.0, rounds 2-4):
//  - pp  = round(px*px) + round(py*py)      (XLA fused mul+reduce, no FMA)
//  - dot = fma(gy, py, round(gx*px))        (Eigen gemm: sequential FMA)
//  - d2  = round(pp - 2*dot)                (2*dot exact; single rounding)

#define GRID_H 256
#define GRID_W 256
#define GRID_G (GRID_H * GRID_W)
#define NPTS   1024
#define BLOCK  256
#define TILE   16
#define TILES_PER_B ((GRID_H / TILE) * (GRID_W / TILE))   // 256

__global__ __launch_bounds__(BLOCK) void nn_tile_kernel(
    const float* __restrict__ R,    // [B, C, N]
    const float* __restrict__ XY,   // [B, 2, N]
    float*       __restrict__ out,  // [B, C, H, W]
    int B, int C, int N)
{
#pragma clang fp contract(off)
    __shared__ float4 cand[NPTS];     // {px, py, pp, as_float(n)}
    __shared__ float  wmin[4];
    __shared__ int    lds_cnt;

    const int blk = blockIdx.x;                 // [0, B*256)
    const int b   = blk >> 8;
    const int t   = blk & 255;
    const int tx  = t & 15, ty = t >> 4;        // tile coords

    const int tid  = threadIdx.x;
    const int lane = tid & 63;
    const int wid  = tid >> 6;

    if (tid == 0) lds_cnt = 0;

    // ---- Phase 1: distance-to-tile-center for all N points (4 per thread)
    const float cx = (float)(tx * TILE + 8) * (1.0f / GRID_W);
    const float cy = (float)(ty * TILE + 8) * (1.0f / GRID_H);

    const float* __restrict__ pxp = XY + (size_t)b * 2 * N;
    const float* __restrict__ pyp = pxp + N;

    float px[4], py[4], dc2[4];
    float local_min = 3.4e38f;
    #pragma unroll
    for (int c = 0; c < 4; ++c) {
        const int n = tid + c * BLOCK;
        px[c] = pxp[n];
        py[c] = pyp[n];
        float dx = px[c] - cx;
        float dy = py[c] - cy;
        dc2[c] = dx * dx + dy * dy;
        local_min = fminf(local_min, dc2[c]);
    }
    // block-wide min of center distances
    #pragma unroll
    for (int off = 32; off >= 1; off >>= 1)
        local_min = fminf(local_min, __shfl_xor(local_min, off));
    if (lane == 0) wmin[wid] = local_min;
    __syncthreads();
    const float m2 = fminf(fminf(wmin[0], wmin[1]), fminf(wmin[2], wmin[3]));
    const float dmin = sqrtf(m2);
    // keep p iff dist(center,p) <= dmin + 2r + eps ; r = sqrt(2)*7.5/256
    const float dthr  = dmin + 0.0828638f + 0.008f;
    const float dthr2 = dthr * dthr;

    // ---- Compaction: ballot + wave-base atomic (order scrambled; phase 2
    //      tie-break restores first-occurrence semantics)
    #pragma unroll
    for (int c = 0; c < 4; ++c) {
        const int n = tid + c * BLOCK;
        const bool keep = (dc2[c] <= dthr2);
        unsigned long long mask = __ballot(keep);
        int prefix = __popcll(mask & ((1ull << lane) - 1ull));
        int wcnt   = __popcll(mask);
        int base = 0;
        if (lane == 0) base = atomicAdd(&lds_cnt, wcnt);
        base = __shfl(base, 0);
        if (keep) {
            float pp = px[c] * px[c] + py[c] * py[c];  // contract off: exact ref rounding
            cand[base + prefix] = make_float4(px[c], py[c], pp, __int_as_float(n));
        }
    }
    __syncthreads();
    const int K = lds_cnt;    // >= 1 (the center-min point always survives)

    // ---- Phase 2: per-cell argmin over K candidates (broadcast LDS reads)
    const int x = tx * TILE + (tid & 15);
    const int y = ty * TILE + (tid >> 4);
    const float gx = ((float)x + 0.5f) * (1.0f / GRID_W);
    const float gy = ((float)y + 0.5f) * (1.0f / GRID_H);

    float best = 3.4e38f;
    int   bi   = 0x7fffffff;
    for (int k = 0; k < K; ++k) {
        float4 q = cand[k];                   // wave-uniform -> broadcast
        int    n = __float_as_int(q.w);
        float  dot = fmaf(gy, q.y, gx * q.x); // Eigen gemm rounding
        float  d2  = fmaf(-2.0f, dot, q.z);   // exact 2*dot, single rounding
        bool better = (d2 < best) || (d2 == best && n < bi);
        best = better ? d2 : best;
        bi   = better ? n  : bi;
    }

    const int g = y * GRID_W + x;
    const float* rb = R + (size_t)b * C * N;
    float*       ob = out + (size_t)b * C * GRID_G;
    #pragma unroll
    for (int c = 0; c < 4; ++c) {
        ob[(size_t)c * GRID_G + g] = rb[(size_t)c * N + bi];
    }
}

extern "C" void kernel_launch(void* const* d_in, const int* in_sizes, int n_in,
                              void* d_out, int out_size, void* d_ws, size_t ws_size,
                              hipStream_t stream) {
    const float* R  = (const float*)d_in[0];   // [B, C, N] f32
    const float* XY = (const float*)d_in[1];   // [B, 2, N] f32
    float* out = (float*)d_out;                // [B, C, H, W] f32

    const int N = NPTS;
    const int B = in_sizes[1] / (2 * N);       // 2
    const int C = in_sizes[0] / (B * N);       // 4

    const int nblocks = B * TILES_PER_B;       // 512
    nn_tile_kernel<<<nblocks, BLOCK, 0, stream>>>(R, XY, out, B, C, N);
}